// Round 9
// baseline (1324.264 us; speedup 1.0000x reference)
//
#include <hip/hip_runtime.h>

#define NB_ 5   // N_BASIS
#define MD_ 5   // MAX_DELAY
#define CHUNK 8
#define AGENT __HIP_MEMORY_SCOPE_AGENT

// ---------------------------------------------------------------------------
// Sense-reversing grid barrier (rare path only).
// ---------------------------------------------------------------------------
__device__ __forceinline__ void grid_barrier(int* cnt, int* gen, int nblk, int& mygen)
{
    __syncthreads();
    if (threadIdx.x == 0) {
        ++mygen;
        int old = __hip_atomic_fetch_add(cnt, 1, __ATOMIC_ACQ_REL, AGENT);
        if (old == nblk - 1) {
            __hip_atomic_store(cnt, 0, __ATOMIC_RELAXED, AGENT);
            __hip_atomic_store(gen, mygen, __ATOMIC_RELEASE, AGENT);
        } else {
            while (__hip_atomic_load(gen, __ATOMIC_ACQUIRE, AGENT) < mygen)
                __builtin_amdgcn_s_sleep(1);
        }
    }
    __syncthreads();
}

// ---------------------------------------------------------------------------
// Optimistic kernel: per-neuron 40-step trajectory with i_rec == 0.
// Bit-exact vs the true trajectory through the first spiking step (inclusive);
// exact everywhere when no spike occurs. Sets spike_flag if any z != 0.
// ---------------------------------------------------------------------------
__global__ __launch_bounds__(256, 2) void optimistic_kernel(
    const float* __restrict__ ext_input,
    const float* __restrict__ decay_g,
    const float* __restrict__ cf_g,
    const float* __restrict__ g_g,
    const float* __restrict__ vth_g,
    const float* __restrict__ vrst_g,
    const float* __restrict__ nrm_g,
    const float* __restrict__ tref_g,
    const float* __restrict__ ek_g,      // (N,2)
    const float* __restrict__ am_g,      // (N,2)
    const float* __restrict__ sd_g,      // n5
    const float* __restrict__ pi_g,      // n5
    float*       __restrict__ out,       // (T,N)
    int*         __restrict__ spike_flag,
    int N, int T)
{
    const int n   = blockIdx.x * blockDim.x + threadIdx.x;
    const bool has = (n < N);
    const int n5  = N * NB_;

    float dec = 0.f, cf = 0.f, gg = 0.f, vth = 0.f, vrst = 0.f, nrm = 0.f, tref = 0.f;
    float ek0 = 0.f, ek1 = 0.f, am0 = 0.f, am1 = 0.f;
    float sdv[NB_], piv[NB_], p[NB_];
    #pragma unroll
    for (int k = 0; k < NB_; ++k) { sdv[k] = 0.f; piv[k] = 0.f; p[k] = 0.f; }
    float v = 0.f, r = 0.f, a0 = 0.f, a1 = 0.f, pz = 0.f;

    if (has) {
        dec = decay_g[n]; cf = cf_g[n]; gg = g_g[n];
        vth = vth_g[n]; vrst = vrst_g[n]; nrm = nrm_g[n]; tref = tref_g[n];
        ek0 = ek_g[2 * n]; ek1 = ek_g[2 * n + 1];
        am0 = am_g[2 * n]; am1 = am_g[2 * n + 1];
        #pragma unroll
        for (int k = 0; k < NB_; ++k) {
            sdv[k] = sd_g[(size_t)n * NB_ + k];
            piv[k] = pi_g[(size_t)n * NB_ + k];
        }
        v = vrst;
    }

    const float* xbase = ext_input + (size_t)n * NB_;
    bool anyspike = false;

    // neuron step body (i_rec == 0), exact reference op order
    auto step = [&](const float x0, const float x1, const float x2,
                    const float x3, const float x4, int t) {
        float ic = 0.0f, pv;
        pv = p[0] * sdv[0] + (0.0f + x0) * piv[0]; p[0] = pv; ic += pv;
        pv = p[1] * sdv[1] + (0.0f + x1) * piv[1]; p[1] = pv; ic += pv;
        pv = p[2] * sdv[2] + (0.0f + x2) * piv[2]; p[2] = pv; ic += pv;
        pv = p[3] * sdv[3] + (0.0f + x3) * piv[3]; p[3] = pv; ic += pv;
        pv = p[4] * sdv[4] + (0.0f + x4) * piv[4]; p[4] = pv; ic += pv;

        a0 = ek0 * a0 + pz * am0;
        a1 = ek1 * a1 + pz * am1;
        float c1 = ic + (a0 + a1) + gg;
        float nv = dec * v + cf * c1;
        if (pz > 0.5f) nv = vrst;

        float vsc = (nv - vth) / nrm;
        float z = (vsc > 0.0f) ? 1.0f : 0.0f;
        if (r > 0.0f) z = 0.0f;
        r = fmaxf(r + z * tref - 1.0f, 0.0f);   // DT = 1.0
        v = nv;
        pz = z;
        out[(size_t)t * N + n] = z;
        anyspike |= (z != 0.0f);
    };

    int tc = 0;
    for (; tc + CHUNK <= T; tc += CHUNK) {
        float xb[CHUNK][NB_];
        if (has) {
            #pragma unroll
            for (int j = 0; j < CHUNK; ++j) {
                const float* xp = xbase + (size_t)(tc + j) * n5;
                #pragma unroll
                for (int k = 0; k < NB_; ++k) xb[j][k] = xp[k];
            }
            #pragma unroll
            for (int j = 0; j < CHUNK; ++j)
                step(xb[j][0], xb[j][1], xb[j][2], xb[j][3], xb[j][4], tc + j);
        }
    }
    for (; tc < T; ++tc) {   // tail (T % CHUNK != 0)
        if (has) {
            const float* xp = xbase + (size_t)tc * n5;
            step(xp[0], xp[1], xp[2], xp[3], xp[4], tc);
        }
    }

    unsigned long long m = __ballot(anyspike);
    if ((threadIdx.x & 63) == 0 && m) atomicAdd(spike_flag, 1);
}

// ---------------------------------------------------------------------------
// Fixup kernel (cooperative): exits immediately when no spike occurred.
// Rare path: zero scratch, then full resimulation from t=0 with the lazy
// push-model edge path and grid barriers (round-8 logic; correctness only).
// ---------------------------------------------------------------------------
__global__ __launch_bounds__(1024, 1) void fixup_kernel(
    const float* __restrict__ weights,
    const float* __restrict__ edge_basis,
    const float* __restrict__ ext_input,
    const float* __restrict__ decay_g,
    const float* __restrict__ cf_g,
    const float* __restrict__ g_g,
    const float* __restrict__ vth_g,
    const float* __restrict__ vrst_g,
    const float* __restrict__ nrm_g,
    const float* __restrict__ tref_g,
    const float* __restrict__ ek_g,
    const float* __restrict__ am_g,
    const float* __restrict__ sd_g,
    const float* __restrict__ pi_g,
    const int*   __restrict__ pre_idx,
    const int*   __restrict__ post_idx,
    float*       __restrict__ out,
    const int*   __restrict__ spike_flag,
    int* bar_cnt, int* bar_gen,
    int* scnt,                            // (T+MD)
    float* i_rec,                         // n5
    unsigned int* zbits,                  // (T+MD)*words32
    int N, int E, int T, int words32, int nblk)
{
    if (__hip_atomic_load(spike_flag, __ATOMIC_RELAXED, AGENT) == 0) return;

    __shared__ int ss[MD_];
    const int tid = blockIdx.x * blockDim.x + threadIdx.x;
    const int nth = gridDim.x * blockDim.x;
    const int n5  = N * NB_;
    const int words64 = words32 >> 1;
    unsigned long long* zb64 = (unsigned long long*)zbits;
    int mygen = 0;

    // ---- zero scratch (optimistic kernel doesn't maintain it) --------------
    for (int i = tid; i < T + MD_; i += nth)
        __hip_atomic_store(&scnt[i], 0, __ATOMIC_RELAXED, AGENT);
    for (int i = tid; i < n5; i += nth)
        __hip_atomic_store(&i_rec[i], 0.0f, __ATOMIC_RELAXED, AGENT);
    for (int i = tid; i < MD_ * words32; i += nth)
        __hip_atomic_store(&zbits[i], 0u, __ATOMIC_RELAXED, AGENT);

    // ---- register state -----------------------------------------------------
    const int  n   = tid;
    const bool has = (n < N);
    float dec = 0.f, cf = 0.f, gg = 0.f, vth = 0.f, vrst = 0.f, nrm = 0.f, tref = 0.f;
    float ek0 = 0.f, ek1 = 0.f, am0 = 0.f, am1 = 0.f;
    float sdv[NB_], piv[NB_], p[NB_];
    #pragma unroll
    for (int k = 0; k < NB_; ++k) { sdv[k] = 0.f; piv[k] = 0.f; p[k] = 0.f; }
    float v = 0.f, r = 0.f, a0 = 0.f, a1 = 0.f, pz = 0.f;
    if (has) {
        dec = decay_g[n]; cf = cf_g[n]; gg = g_g[n];
        vth = vth_g[n]; vrst = vrst_g[n]; nrm = nrm_g[n]; tref = tref_g[n];
        ek0 = ek_g[2 * n]; ek1 = ek_g[2 * n + 1];
        am0 = am_g[2 * n]; am1 = am_g[2 * n + 1];
        #pragma unroll
        for (int k = 0; k < NB_; ++k) {
            sdv[k] = sd_g[(size_t)n * NB_ + k];
            piv[k] = pi_g[(size_t)n * NB_ + k];
        }
        v = vrst;
    }

    float xv[NB_] = {0.f, 0.f, 0.f, 0.f, 0.f};
    if (has) {
        const float* xp = ext_input + (size_t)n * NB_;
        #pragma unroll
        for (int k = 0; k < NB_; ++k) xv[k] = xp[k];
    }

    grid_barrier(bar_cnt, bar_gen, nblk, mygen);   // zero pass complete

    for (int t = 0; t < T; ++t) {
        if (threadIdx.x < MD_)
            ss[threadIdx.x] = __hip_atomic_load(&scnt[t + threadIdx.x],
                                                __ATOMIC_RELAXED, AGENT);
        __syncthreads();
        int scw = ss[0] + ss[1] + ss[2] + ss[3] + ss[4];

        float ir0 = 0.f, ir1 = 0.f, ir2 = 0.f, ir3 = 0.f, ir4 = 0.f;
        if (scw > 0) {
            for (int e = tid; e < E; e += nth) {
                int pre = pre_idx[e];
                int d  = pre / N;
                int nn = pre - d * N;
                int row = t + (MD_ - 1 - d);
                unsigned w = __hip_atomic_load(
                    &zbits[(size_t)row * words32 + (nn >> 5)],
                    __ATOMIC_RELAXED, AGENT);
                if ((w >> (nn & 31)) & 1u) {
                    float wt = weights[e];
                    const float* bs = edge_basis + (size_t)e * NB_;
                    float* ir = i_rec + (size_t)post_idx[e] * NB_;
                    atomicAdd(ir + 0, wt * bs[0]);
                    atomicAdd(ir + 1, wt * bs[1]);
                    atomicAdd(ir + 2, wt * bs[2]);
                    atomicAdd(ir + 3, wt * bs[3]);
                    atomicAdd(ir + 4, wt * bs[4]);
                }
            }
            grid_barrier(bar_cnt, bar_gen, nblk, mygen);
            if (has) {
                float* ir = i_rec + (size_t)n * NB_;
                ir0 = __hip_atomic_load(ir + 0, __ATOMIC_RELAXED, AGENT);
                ir1 = __hip_atomic_load(ir + 1, __ATOMIC_RELAXED, AGENT);
                ir2 = __hip_atomic_load(ir + 2, __ATOMIC_RELAXED, AGENT);
                ir3 = __hip_atomic_load(ir + 3, __ATOMIC_RELAXED, AGENT);
                ir4 = __hip_atomic_load(ir + 4, __ATOMIC_RELAXED, AGENT);
                __hip_atomic_store(ir + 0, 0.0f, __ATOMIC_RELAXED, AGENT);
                __hip_atomic_store(ir + 1, 0.0f, __ATOMIC_RELAXED, AGENT);
                __hip_atomic_store(ir + 2, 0.0f, __ATOMIC_RELAXED, AGENT);
                __hip_atomic_store(ir + 3, 0.0f, __ATOMIC_RELAXED, AGENT);
                __hip_atomic_store(ir + 4, 0.0f, __ATOMIC_RELAXED, AGENT);
            }
        }

        float z = 0.0f;
        if (has) {
            float ic = 0.0f, pv;
            pv = p[0] * sdv[0] + (ir0 + xv[0]) * piv[0]; p[0] = pv; ic += pv;
            pv = p[1] * sdv[1] + (ir1 + xv[1]) * piv[1]; p[1] = pv; ic += pv;
            pv = p[2] * sdv[2] + (ir2 + xv[2]) * piv[2]; p[2] = pv; ic += pv;
            pv = p[3] * sdv[3] + (ir3 + xv[3]) * piv[3]; p[3] = pv; ic += pv;
            pv = p[4] * sdv[4] + (ir4 + xv[4]) * piv[4]; p[4] = pv; ic += pv;

            a0 = ek0 * a0 + pz * am0;
            a1 = ek1 * a1 + pz * am1;
            float c1 = ic + (a0 + a1) + gg;
            float nv = dec * v + cf * c1;
            if (pz > 0.5f) nv = vrst;

            float vsc = (nv - vth) / nrm;
            z = (vsc > 0.0f) ? 1.0f : 0.0f;
            if (r > 0.0f) z = 0.0f;
            r = fmaxf(r + z * tref - 1.0f, 0.0f);
            v = nv;
            pz = z;
            out[(size_t)t * N + n] = z;
        }

        unsigned long long m = __ballot(z != 0.0f);
        int wv = tid >> 6;
        if ((threadIdx.x & 63) == 0 && (wv << 6) < N) {
            __hip_atomic_store(zb64 + (size_t)(t + MD_) * words64 + wv, m,
                               __ATOMIC_RELAXED, AGENT);
            if (m) __hip_atomic_fetch_add(&scnt[t + MD_], (int)__popcll(m),
                                          __ATOMIC_RELAXED, AGENT);
        }

        if (has && t + 1 < T) {
            const float* xp = ext_input + (size_t)(t + 1) * n5 + (size_t)n * NB_;
            #pragma unroll
            for (int k = 0; k < NB_; ++k) xv[k] = xp[k];
        }

        if (t + 1 < T)
            grid_barrier(bar_cnt, bar_gen, nblk, mygen);
    }
}

// ---------------------------------------------------------------------------
// Launcher: tiny memset + optimistic + fixup (3 dispatches).
// ---------------------------------------------------------------------------
extern "C" void kernel_launch(void* const* d_in, const int* in_sizes, int n_in,
                              void* d_out, int out_size, void* d_ws, size_t ws_size,
                              hipStream_t stream)
{
    const float* weights        = (const float*)d_in[0];
    const float* edge_basis     = (const float*)d_in[1];
    const float* ext_input      = (const float*)d_in[2];
    const float* decay          = (const float*)d_in[3];
    const float* current_factor = (const float*)d_in[4];
    const float* gathered_g     = (const float*)d_in[5];
    const float* v_th           = (const float*)d_in[6];
    const float* v_reset        = (const float*)d_in[7];
    const float* normalizer     = (const float*)d_in[8];
    const float* t_ref          = (const float*)d_in[9];
    const float* exp_dt_k       = (const float*)d_in[10];
    const float* asc_amps       = (const float*)d_in[11];
    const float* syn_decay      = (const float*)d_in[12];
    const float* psc_initial    = (const float*)d_in[13];
    const int*   pre_idx        = (const int*)d_in[14];
    const int*   post_idx       = (const int*)d_in[15];

    const int E  = in_sizes[0];
    const int N  = in_sizes[3];
    const int n5 = N * NB_;
    const int T  = in_sizes[2] / n5;          // B = 1

    const int words64 = (N + 63) / 64;        // 782
    const int words32 = words64 * 2;          // 1564

    float* out = (float*)d_out;

    // ---- workspace layout ---------------------------------------------------
    char* wsb = (char*)d_ws;
    size_t o = 0;
    int* bar_cnt    = (int*)(wsb + o); o += 8;
    int* bar_gen    = (int*)(wsb + o); o += 8;
    int* spike_flag = (int*)(wsb + o); o += 16;
    size_t zero_bytes = o;                     // 32 B control block
    int*   scnt  = (int*)(wsb + o);   o += (size_t)(T + MD_) * 4;
    o = (o + 15) & ~(size_t)15;
    float* i_rec = (float*)(wsb + o); o += (size_t)n5 * 4;
    o = (o + 15) & ~(size_t)15;
    unsigned int* zbits = (unsigned int*)(wsb + o);
    o += (size_t)(T + MD_) * words32 * 4;

    hipMemsetAsync(d_ws, 0, zero_bytes, stream);   // 32 B: barrier + flag

    // ---- optimistic trajectory (the real work) ------------------------------
    const int nblkO = (N + 255) / 256;        // 196
    optimistic_kernel<<<nblkO, 256, 0, stream>>>(
        ext_input, decay, current_factor, gathered_g,
        v_th, v_reset, normalizer, t_ref,
        exp_dt_k, asc_amps, syn_decay, psc_initial,
        out, spike_flag, N, T);

    // ---- fixup (uniform immediate exit when no spikes) -----------------------
    const int BLK  = 1024;
    const int nblk = (N + BLK - 1) / BLK;     // 49 blocks, co-resident
    void* args[] = {
        (void*)&weights, (void*)&edge_basis, (void*)&ext_input,
        (void*)&decay, (void*)&current_factor, (void*)&gathered_g,
        (void*)&v_th, (void*)&v_reset, (void*)&normalizer, (void*)&t_ref,
        (void*)&exp_dt_k, (void*)&asc_amps, (void*)&syn_decay, (void*)&psc_initial,
        (void*)&pre_idx, (void*)&post_idx,
        (void*)&out, (void*)&spike_flag,
        (void*)&bar_cnt, (void*)&bar_gen, (void*)&scnt, (void*)&i_rec, (void*)&zbits,
        (void*)&N, (void*)&E, (void*)&T, (void*)&words32, (void*)&nblk
    };
    hipLaunchCooperativeKernel((void*)fixup_kernel, dim3(nblk), dim3(BLK), args,
                               0, stream);
}

// Round 10
// 834.267 us; speedup vs baseline: 1.5873x; 1.5873x over previous
//
#include <hip/hip_runtime.h>

#define NB_ 5      // N_BASIS
#define MD_ 5      // MAX_DELAY
#define CSL 128    // post-neurons per coarse bucket (power of 2)
#define CH  4096   // edges per block in hist/partition passes

// ---------------------------------------------------------------------------
// Build (per launch): two-pass counting sort of edges by POST neuron.
// part[] record uint2: { x = slotbit | (localpost<<18), y = eid }
//   slotbit(e) = (MD-1-d)*bitstride + n  (< 5*50048 = 250240 < 2^18)
//   localpost  = post & (CSL-1)
// Final: inSlot[i] (18-bit slotbit), inEid[i], sorted by post;
//        row_ptr[p] = inclusive end of post p's run.
// ---------------------------------------------------------------------------

__global__ __launch_bounds__(256) void init_kernel(
    const float* __restrict__ decay, const float* __restrict__ cf,
    const float* __restrict__ g,     const float* __restrict__ vth,
    const float* __restrict__ vrst,  const float* __restrict__ nrm,
    const float* __restrict__ tref,  const float* __restrict__ ek,
    const float* __restrict__ am,
    float4* __restrict__ pk, float* __restrict__ v, float* __restrict__ r,
    float* __restrict__ asc, float* __restrict__ psc, int N)
{
    int n = blockIdx.x * blockDim.x + threadIdx.x;
    if (n >= N) return;
    pk[3 * n]     = make_float4(decay[n], cf[n], g[n], vth[n]);
    pk[3 * n + 1] = make_float4(vrst[n], nrm[n], tref[n], ek[2 * n]);
    pk[3 * n + 2] = make_float4(ek[2 * n + 1], am[2 * n], am[2 * n + 1], 0.0f);
    v[n] = vrst[n];
    r[n] = 0.0f;
    asc[2 * n] = 0.0f; asc[2 * n + 1] = 0.0f;
    #pragma unroll
    for (int k = 0; k < NB_; ++k) psc[(size_t)n * NB_ + k] = 0.0f;
}

__global__ __launch_bounds__(256) void coarse_hist_kernel(
    const int* __restrict__ post_idx, int* __restrict__ chist, int E)
{
    __shared__ int cntL[512];
    int t = threadIdx.x;
    cntL[t] = 0; cntL[t + 256] = 0;
    __syncthreads();
    int e0 = blockIdx.x * CH;
    int e1 = min(e0 + CH, E);
    for (int e = e0 + t; e < e1; e += 256)
        atomicAdd(&cntL[post_idx[e] >> 7], 1);
    __syncthreads();
    for (int b = t; b < 512; b += 256)
        if (cntL[b]) atomicAdd(&chist[b], cntL[b]);
}

// 1 block: coarse_base[0]=0, coarse_base[i+1]=inclusive scan; coarse_ptr=excl
__global__ __launch_bounds__(256) void scan_coarse_kernel(
    const int* __restrict__ chist, int* __restrict__ coarse_base,
    int* __restrict__ coarse_ptr, int NC)
{
    __shared__ int tmp[256];
    int t = threadIdx.x;
    int i0 = 2 * t, i1 = 2 * t + 1;
    int a = (i0 < NC) ? chist[i0] : 0;
    int b = (i1 < NC) ? chist[i1] : 0;
    int s = a + b;
    tmp[t] = s;
    __syncthreads();
    for (int off = 1; off < 256; off <<= 1) {
        int y = (t >= off) ? tmp[t - off] : 0;
        __syncthreads();
        tmp[t] += y;
        __syncthreads();
    }
    int ep = tmp[t] - s;
    if (t == 0) coarse_base[0] = 0;
    if (i0 < NC) { coarse_ptr[i0] = ep;     coarse_base[i0 + 1] = ep + a; }
    if (i1 < NC) { coarse_ptr[i1] = ep + a; coarse_base[i1 + 1] = ep + s; }
}

__global__ __launch_bounds__(256) void partition_kernel(
    const int* __restrict__ pre_idx,
    const int* __restrict__ post_idx,
    int* __restrict__ coarse_ptr,
    uint2* __restrict__ part,
    int E, int N, int bitstride)
{
    __shared__ int cntL[512];
    __shared__ int posL[512];
    int t = threadIdx.x;
    cntL[t] = 0; cntL[t + 256] = 0;
    __syncthreads();
    int e0 = blockIdx.x * CH;
    int e1 = min(e0 + CH, E);
    for (int e = e0 + t; e < e1; e += 256)
        atomicAdd(&cntL[post_idx[e] >> 7], 1);
    __syncthreads();
    for (int b = t; b < 512; b += 256)
        posL[b] = cntL[b] ? atomicAdd(&coarse_ptr[b], cntL[b]) : 0;
    __syncthreads();
    for (int e = e0 + t; e < e1; e += 256) {
        int post = post_idx[e];
        int pre  = pre_idx[e];
        int d = pre / N;
        unsigned slotbit = (unsigned)((MD_ - 1 - d) * bitstride + (pre - d * N));
        int p = atomicAdd(&posL[post >> 7], 1);
        uint2 q;
        q.x = slotbit | ((unsigned)(post & (CSL - 1)) << 18);
        q.y = (unsigned)e;
        part[p] = q;
    }
}

// one block per coarse bucket: LDS counting sort over CSL local post slots;
// emits split arrays inSlot / inEid.
__global__ __launch_bounds__(256) void bucket_sort_kernel(
    const int* __restrict__ coarse_base,
    const uint2* __restrict__ part,
    unsigned* __restrict__ inSlot,
    unsigned* __restrict__ inEid,
    int* __restrict__ row_ptr, int N)
{
    __shared__ int h[CSL];
    __shared__ int sc_[CSL];
    __shared__ int pos_[CSL];
    int c = blockIdx.x, t = threadIdx.x;
    int lo = coarse_base[c], hi = coarse_base[c + 1];
    if (t < CSL) h[t] = 0;
    __syncthreads();
    for (int i = lo + t; i < hi; i += 256)
        atomicAdd(&h[part[i].x >> 18], 1);
    __syncthreads();
    if (t < CSL) sc_[t] = h[t];
    __syncthreads();
    for (int off = 1; off < CSL; off <<= 1) {
        int y = 0;
        if (t < CSL && t >= off) y = sc_[t - off];
        __syncthreads();
        if (t < CSL && t >= off) sc_[t] += y;
        __syncthreads();
    }
    if (t < CSL) {
        pos_[t] = lo + sc_[t] - h[t];            // exclusive start
        int gp = c * CSL + t;
        if (gp < N) row_ptr[gp] = lo + sc_[t];   // inclusive end
    }
    __syncthreads();
    for (int i = lo + t; i < hi; i += 256) {
        uint2 q = part[i];
        int dst = atomicAdd(&pos_[q.x >> 18], 1);
        inSlot[dst] = q.x & 0x3FFFFu;
        inEid[dst]  = q.y;
    }
}

// ---------------------------------------------------------------------------
// Fused per-step kernel: pull-model edge gather (register acc) + neuron update.
// No LDS staging, no i_rec buffer, no __syncthreads.
// ---------------------------------------------------------------------------

__global__ __launch_bounds__(256) void step_kernel(
    const float* __restrict__ x_t,        // ext_input + t*n5
    float*       __restrict__ psc,        // n5
    const float* __restrict__ sd,         // syn_decay
    const float* __restrict__ pi,         // psc_initial
    const float4* __restrict__ pk,        // {decay,cf,g,vth}{vrst,nrm,tref,ek0}{ek1,am0,am1,_}
    float* __restrict__ v,
    float* __restrict__ r,
    float* __restrict__ asc,              // (N,2)
    const int* __restrict__ scnt_t,       // scnt + t  (5-slot window counts)
    int*       __restrict__ scnt_new,     // scnt + t + MD
    const unsigned* __restrict__ zwin,    // zbits + t*words32 (5 contiguous rows)
    const unsigned* __restrict__ zrow_prev,
    unsigned*       __restrict__ zrow_new,
    const int*      __restrict__ row_ptr, // by-post CSR inclusive ends
    const unsigned* __restrict__ inSlot,
    const unsigned* __restrict__ inEid,
    const float*    __restrict__ weights,
    const float*    __restrict__ edge_basis,
    float* __restrict__ out_t,
    int N)
{
    int n = blockIdx.x * blockDim.x + threadIdx.x;
    int scw = scnt_t[0] + scnt_t[1] + scnt_t[2] + scnt_t[3] + scnt_t[4];
    bool has = (n < N);

    float z = 0.0f;
    if (has) {
        // ---- pull-model recurrent input (registers) -----------------------
        float ir0 = 0.f, ir1 = 0.f, ir2 = 0.f, ir3 = 0.f, ir4 = 0.f;
        if (scw > 0) {
            int s0 = n ? row_ptr[n - 1] : 0;
            int s1 = row_ptr[n];
            for (int i = s0; i < s1; ++i) {
                unsigned sb = inSlot[i];
                if ((zwin[sb >> 5] >> (sb & 31)) & 1u) {
                    int e = (int)inEid[i];
                    float w = weights[e];
                    const float* bs = edge_basis + (size_t)e * NB_;
                    ir0 += w * bs[0];
                    ir1 += w * bs[1];
                    ir2 += w * bs[2];
                    ir3 += w * bs[3];
                    ir4 += w * bs[4];
                }
            }
        }

        // ---- psc recurrence + input current (k ascending, ref order) ------
        const float* xp  = x_t + (size_t)n * NB_;
        float*       pp  = psc + (size_t)n * NB_;
        const float* sdp = sd  + (size_t)n * NB_;
        const float* pip = pi  + (size_t)n * NB_;
        float ic = 0.0f, pv;
        pv = pp[0] * sdp[0] + (ir0 + xp[0]) * pip[0]; pp[0] = pv; ic += pv;
        pv = pp[1] * sdp[1] + (ir1 + xp[1]) * pip[1]; pp[1] = pv; ic += pv;
        pv = pp[2] * sdp[2] + (ir2 + xp[2]) * pip[2]; pp[2] = pv; ic += pv;
        pv = pp[3] * sdp[3] + (ir3 + xp[3]) * pip[3]; pp[3] = pv; ic += pv;
        pv = pp[4] * sdp[4] + (ir4 + xp[4]) * pip[4]; pp[4] = pv; ic += pv;

        float4 P0 = pk[3 * n], P1 = pk[3 * n + 1], P2 = pk[3 * n + 2];

        unsigned pwd = zrow_prev[n >> 5];
        float pz = ((pwd >> (n & 31)) & 1u) ? 1.0f : 0.0f;

        float a0 = P1.w * asc[2 * n]     + pz * P2.y;
        float a1 = P2.x * asc[2 * n + 1] + pz * P2.z;
        asc[2 * n]     = a0;
        asc[2 * n + 1] = a1;

        float c1 = ic + (a0 + a1) + P0.z;
        float nv = P0.x * v[n] + P0.y * c1;
        if (pz > 0.5f) nv = P1.x;

        float vsc = (nv - P0.w) / P1.y;
        z = (vsc > 0.0f) ? 1.0f : 0.0f;
        float rr = r[n];
        if (rr > 0.0f) z = 0.0f;

        r[n] = fmaxf(rr + z * P1.z - 1.0f, 0.0f);   // DT = 1.0
        v[n] = nv;
        out_t[n] = z;
    }

    // bit-pack this step's spikes: one u64 store per wave
    unsigned long long m = __ballot(z != 0.0f);
    int gtid = blockIdx.x * blockDim.x + threadIdx.x;
    int wv = gtid >> 6;
    if ((threadIdx.x & 63) == 0 && (wv << 6) < N) {
        *(unsigned long long*)(zrow_new + (wv << 1)) = m;
        if (m) atomicAdd(scnt_new, __popcll(m));
    }
}

// ---------------------------------------------------------------------------
// Launcher
// ---------------------------------------------------------------------------

extern "C" void kernel_launch(void* const* d_in, const int* in_sizes, int n_in,
                              void* d_out, int out_size, void* d_ws, size_t ws_size,
                              hipStream_t stream)
{
    const float* weights        = (const float*)d_in[0];
    const float* edge_basis     = (const float*)d_in[1];
    const float* ext_input      = (const float*)d_in[2];
    const float* decay          = (const float*)d_in[3];
    const float* current_factor = (const float*)d_in[4];
    const float* gathered_g     = (const float*)d_in[5];
    const float* v_th           = (const float*)d_in[6];
    const float* v_reset        = (const float*)d_in[7];
    const float* normalizer     = (const float*)d_in[8];
    const float* t_ref          = (const float*)d_in[9];
    const float* exp_dt_k       = (const float*)d_in[10];
    const float* asc_amps       = (const float*)d_in[11];
    const float* syn_decay      = (const float*)d_in[12];
    const float* psc_initial    = (const float*)d_in[13];
    const int*   pre_idx        = (const int*)d_in[14];
    const int*   post_idx       = (const int*)d_in[15];

    const int E  = in_sizes[0];
    const int N  = in_sizes[3];
    const int n5 = N * NB_;
    const int T  = in_sizes[2] / n5;            // B = 1

    const int words64   = (N + 63) / 64;        // 782
    const int words32   = words64 * 2;          // 1564
    const int bitstride = words32 * 32;         // 50048
    const int NC        = (N + CSL - 1) / CSL;  // 391

    float* out = (float*)d_out;

    // ---- workspace layout ---------------------------------------------------
    char* wsb = (char*)d_ws;
    size_t o = 0;
    // zero group (one small memset):
    int* chist = (int*)(wsb + o);  o += 512 * 4;
    int* scnt  = (int*)(wsb + o);  o += (size_t)(T + MD_) * 4;
    o = (o + 15) & ~(size_t)15;
    unsigned* zbits = (unsigned*)(wsb + o);
    size_t zero_bytes = o + (size_t)MD_ * words32 * 4;   // zbits head (rows 0..4)
    o += (size_t)(T + MD_) * words32 * 4;
    // non-zeroed:
    o = (o + 15) & ~(size_t)15;
    float*  psc         = (float*)(wsb + o);  o += (size_t)n5 * 4;
    float*  v           = (float*)(wsb + o);  o += (size_t)N * 4;
    float*  r           = (float*)(wsb + o);  o += (size_t)N * 4;
    float*  asc         = (float*)(wsb + o);  o += (size_t)2 * N * 4;
    float4* pk          = (float4*)(wsb + o); o += (size_t)N * 12 * 4;
    int*    row_ptr     = (int*)(wsb + o);    o += (size_t)N * 4;
    int*    coarse_base = (int*)(wsb + o);    o += 513 * 4;
    int*    coarse_ptr  = (int*)(wsb + o);    o += 512 * 4;
    o = (o + 15) & ~(size_t)15;
    uint2*    part      = (uint2*)(wsb + o);    o += (size_t)E * 8;
    unsigned* inSlot    = (unsigned*)(wsb + o); o += (size_t)E * 4;
    unsigned* inEid     = (unsigned*)(wsb + o); o += (size_t)E * 4;

    // ---- build (every launch; graph replays everything) --------------------
    hipMemsetAsync(d_ws, 0, zero_bytes, stream);   // ~34 KB

    init_kernel<<<(N + 255) / 256, 256, 0, stream>>>(
        decay, current_factor, gathered_g, v_th, v_reset, normalizer, t_ref,
        exp_dt_k, asc_amps, pk, v, r, asc, psc, N);

    const int nbe = (E + CH - 1) / CH;   // 489
    coarse_hist_kernel<<<nbe, 256, 0, stream>>>(post_idx, chist, E);
    scan_coarse_kernel<<<1, 256, 0, stream>>>(chist, coarse_base, coarse_ptr, NC);
    partition_kernel<<<nbe, 256, 0, stream>>>(
        pre_idx, post_idx, coarse_ptr, part, E, N, bitstride);
    bucket_sort_kernel<<<NC, 256, 0, stream>>>(
        coarse_base, part, inSlot, inEid, row_ptr, N);

    // ---- time loop: ONE lean kernel per step --------------------------------
    const int nblk = (N + 255) / 256;    // 196
    for (int t = 0; t < T; ++t) {
        step_kernel<<<nblk, 256, 0, stream>>>(
            ext_input + (size_t)t * n5,
            psc, syn_decay, psc_initial,
            pk, v, r, asc,
            scnt + t, scnt + t + MD_,
            zbits + (size_t)t * words32,
            zbits + (size_t)(t + MD_ - 1) * words32,
            zbits + (size_t)(t + MD_) * words32,
            row_ptr, inSlot, inEid, weights, edge_basis,
            out + (size_t)t * N,
            N);
    }
}

// Round 11
// 833.677 us; speedup vs baseline: 1.5885x; 1.0007x over previous
//
#include <hip/hip_runtime.h>

#define NB_ 5      // N_BASIS
#define MD_ 5      // MAX_DELAY
#define CSL 128    // post-neurons per coarse bucket (power of 2)
#define CH  4096   // edges per block in hist/partition passes

// ---------------------------------------------------------------------------
// Build (per launch): two-pass counting sort of edges by POST neuron.
// part[] record uint2: { x = slotbit | (localpost<<18), y = eid }
//   slotbit(e) = (MD-1-d)*bitstride + n  (< 5*50048 = 250240 < 2^18)
//   localpost  = post & (CSL-1)
// Final: inSlot[i] (18-bit slotbit), inEid[i], sorted by post;
//        row_ptr[p] = inclusive end of post p's run.
// ---------------------------------------------------------------------------

__global__ __launch_bounds__(256) void init_kernel(
    const float* __restrict__ decay, const float* __restrict__ cf,
    const float* __restrict__ g,     const float* __restrict__ vth,
    const float* __restrict__ vrst,  const float* __restrict__ nrm,
    const float* __restrict__ tref,  const float* __restrict__ ek,
    const float* __restrict__ am,
    float4* __restrict__ pk, float* __restrict__ v, float* __restrict__ r,
    float* __restrict__ asc, float* __restrict__ psc, int N)
{
    int n = blockIdx.x * blockDim.x + threadIdx.x;
    if (n >= N) return;
    pk[3 * n]     = make_float4(decay[n], cf[n], g[n], vth[n]);
    pk[3 * n + 1] = make_float4(vrst[n], nrm[n], tref[n], ek[2 * n]);
    pk[3 * n + 2] = make_float4(ek[2 * n + 1], am[2 * n], am[2 * n + 1], 0.0f);
    v[n] = vrst[n];
    r[n] = 0.0f;
    asc[2 * n] = 0.0f; asc[2 * n + 1] = 0.0f;
    #pragma unroll
    for (int k = 0; k < NB_; ++k) psc[(size_t)n * NB_ + k] = 0.0f;
}

__global__ __launch_bounds__(256) void coarse_hist_kernel(
    const int* __restrict__ post_idx, int* __restrict__ chist, int E)
{
    __shared__ int cntL[512];
    int t = threadIdx.x;
    cntL[t] = 0; cntL[t + 256] = 0;
    __syncthreads();
    int e0 = blockIdx.x * CH;
    int e1 = min(e0 + CH, E);
    for (int e = e0 + t; e < e1; e += 256)
        atomicAdd(&cntL[post_idx[e] >> 7], 1);
    __syncthreads();
    for (int b = t; b < 512; b += 256)
        if (cntL[b]) atomicAdd(&chist[b], cntL[b]);
}

// 1 block: coarse_base[0]=0, coarse_base[i+1]=inclusive scan; coarse_ptr=excl
__global__ __launch_bounds__(256) void scan_coarse_kernel(
    const int* __restrict__ chist, int* __restrict__ coarse_base,
    int* __restrict__ coarse_ptr, int NC)
{
    __shared__ int tmp[256];
    int t = threadIdx.x;
    int i0 = 2 * t, i1 = 2 * t + 1;
    int a = (i0 < NC) ? chist[i0] : 0;
    int b = (i1 < NC) ? chist[i1] : 0;
    int s = a + b;
    tmp[t] = s;
    __syncthreads();
    for (int off = 1; off < 256; off <<= 1) {
        int y = (t >= off) ? tmp[t - off] : 0;
        __syncthreads();
        tmp[t] += y;
        __syncthreads();
    }
    int ep = tmp[t] - s;
    if (t == 0) coarse_base[0] = 0;
    if (i0 < NC) { coarse_ptr[i0] = ep;     coarse_base[i0 + 1] = ep + a; }
    if (i1 < NC) { coarse_ptr[i1] = ep + a; coarse_base[i1 + 1] = ep + s; }
}

__global__ __launch_bounds__(256) void partition_kernel(
    const int* __restrict__ pre_idx,
    const int* __restrict__ post_idx,
    int* __restrict__ coarse_ptr,
    uint2* __restrict__ part,
    int E, int N, int bitstride)
{
    __shared__ int cntL[512];
    __shared__ int posL[512];
    int t = threadIdx.x;
    cntL[t] = 0; cntL[t + 256] = 0;
    __syncthreads();
    int e0 = blockIdx.x * CH;
    int e1 = min(e0 + CH, E);
    for (int e = e0 + t; e < e1; e += 256)
        atomicAdd(&cntL[post_idx[e] >> 7], 1);
    __syncthreads();
    for (int b = t; b < 512; b += 256)
        posL[b] = cntL[b] ? atomicAdd(&coarse_ptr[b], cntL[b]) : 0;
    __syncthreads();
    for (int e = e0 + t; e < e1; e += 256) {
        int post = post_idx[e];
        int pre  = pre_idx[e];
        int d = pre / N;
        unsigned slotbit = (unsigned)((MD_ - 1 - d) * bitstride + (pre - d * N));
        int p = atomicAdd(&posL[post >> 7], 1);
        uint2 q;
        q.x = slotbit | ((unsigned)(post & (CSL - 1)) << 18);
        q.y = (unsigned)e;
        part[p] = q;
    }
}

// one block per coarse bucket: LDS counting sort over CSL local post slots;
// emits split arrays inSlot / inEid.
__global__ __launch_bounds__(256) void bucket_sort_kernel(
    const int* __restrict__ coarse_base,
    const uint2* __restrict__ part,
    unsigned* __restrict__ inSlot,
    unsigned* __restrict__ inEid,
    int* __restrict__ row_ptr, int N)
{
    __shared__ int h[CSL];
    __shared__ int sc_[CSL];
    __shared__ int pos_[CSL];
    int c = blockIdx.x, t = threadIdx.x;
    int lo = coarse_base[c], hi = coarse_base[c + 1];
    if (t < CSL) h[t] = 0;
    __syncthreads();
    for (int i = lo + t; i < hi; i += 256)
        atomicAdd(&h[part[i].x >> 18], 1);
    __syncthreads();
    if (t < CSL) sc_[t] = h[t];
    __syncthreads();
    for (int off = 1; off < CSL; off <<= 1) {
        int y = 0;
        if (t < CSL && t >= off) y = sc_[t - off];
        __syncthreads();
        if (t < CSL && t >= off) sc_[t] += y;
        __syncthreads();
    }
    if (t < CSL) {
        pos_[t] = lo + sc_[t] - h[t];            // exclusive start
        int gp = c * CSL + t;
        if (gp < N) row_ptr[gp] = lo + sc_[t];   // inclusive end
    }
    __syncthreads();
    for (int i = lo + t; i < hi; i += 256) {
        uint2 q = part[i];
        int dst = atomicAdd(&pos_[q.x >> 18], 1);
        inSlot[dst] = q.x & 0x3FFFFu;
        inEid[dst]  = q.y;
    }
}

// ---------------------------------------------------------------------------
// Fused per-step kernel: pull-model edge gather (register acc) + neuron update.
// No LDS staging, no i_rec buffer, no __syncthreads.
// ---------------------------------------------------------------------------

__global__ __launch_bounds__(256) void step_kernel(
    const float* __restrict__ x_t,        // ext_input + t*n5
    float*       __restrict__ psc,        // n5
    const float* __restrict__ sd,         // syn_decay
    const float* __restrict__ pi,         // psc_initial
    const float4* __restrict__ pk,        // {decay,cf,g,vth}{vrst,nrm,tref,ek0}{ek1,am0,am1,_}
    float* __restrict__ v,
    float* __restrict__ r,
    float* __restrict__ asc,              // (N,2)
    const int* __restrict__ scnt_t,       // scnt + t  (5-slot window counts)
    int*       __restrict__ scnt_new,     // scnt + t + MD
    const unsigned* __restrict__ zwin,    // zbits + t*words32 (5 contiguous rows)
    const unsigned* __restrict__ zrow_prev,
    unsigned*       __restrict__ zrow_new,
    const int*      __restrict__ row_ptr, // by-post CSR inclusive ends
    const unsigned* __restrict__ inSlot,
    const unsigned* __restrict__ inEid,
    const float*    __restrict__ weights,
    const float*    __restrict__ edge_basis,
    float* __restrict__ out_t,
    int N)
{
    int n = blockIdx.x * blockDim.x + threadIdx.x;
    int scw = scnt_t[0] + scnt_t[1] + scnt_t[2] + scnt_t[3] + scnt_t[4];
    bool has = (n < N);

    float z = 0.0f;
    if (has) {
        // ---- pull-model recurrent input (registers) -----------------------
        float ir0 = 0.f, ir1 = 0.f, ir2 = 0.f, ir3 = 0.f, ir4 = 0.f;
        if (scw > 0) {
            int s0 = n ? row_ptr[n - 1] : 0;
            int s1 = row_ptr[n];
            for (int i = s0; i < s1; ++i) {
                unsigned sb = inSlot[i];
                if ((zwin[sb >> 5] >> (sb & 31)) & 1u) {
                    int e = (int)inEid[i];
                    float w = weights[e];
                    const float* bs = edge_basis + (size_t)e * NB_;
                    ir0 += w * bs[0];
                    ir1 += w * bs[1];
                    ir2 += w * bs[2];
                    ir3 += w * bs[3];
                    ir4 += w * bs[4];
                }
            }
        }

        // ---- psc recurrence + input current (k ascending, ref order) ------
        const float* xp  = x_t + (size_t)n * NB_;
        float*       pp  = psc + (size_t)n * NB_;
        const float* sdp = sd  + (size_t)n * NB_;
        const float* pip = pi  + (size_t)n * NB_;
        float ic = 0.0f, pv;
        pv = pp[0] * sdp[0] + (ir0 + xp[0]) * pip[0]; pp[0] = pv; ic += pv;
        pv = pp[1] * sdp[1] + (ir1 + xp[1]) * pip[1]; pp[1] = pv; ic += pv;
        pv = pp[2] * sdp[2] + (ir2 + xp[2]) * pip[2]; pp[2] = pv; ic += pv;
        pv = pp[3] * sdp[3] + (ir3 + xp[3]) * pip[3]; pp[3] = pv; ic += pv;
        pv = pp[4] * sdp[4] + (ir4 + xp[4]) * pip[4]; pp[4] = pv; ic += pv;

        float4 P0 = pk[3 * n], P1 = pk[3 * n + 1], P2 = pk[3 * n + 2];

        unsigned pwd = zrow_prev[n >> 5];
        float pz = ((pwd >> (n & 31)) & 1u) ? 1.0f : 0.0f;

        float a0 = P1.w * asc[2 * n]     + pz * P2.y;
        float a1 = P2.x * asc[2 * n + 1] + pz * P2.z;
        asc[2 * n]     = a0;
        asc[2 * n + 1] = a1;

        float c1 = ic + (a0 + a1) + P0.z;
        float nv = P0.x * v[n] + P0.y * c1;
        if (pz > 0.5f) nv = P1.x;

        float vsc = (nv - P0.w) / P1.y;
        z = (vsc > 0.0f) ? 1.0f : 0.0f;
        float rr = r[n];
        if (rr > 0.0f) z = 0.0f;

        r[n] = fmaxf(rr + z * P1.z - 1.0f, 0.0f);   // DT = 1.0
        v[n] = nv;
        out_t[n] = z;
    }

    // bit-pack this step's spikes: one u64 store per wave
    unsigned long long m = __ballot(z != 0.0f);
    int gtid = blockIdx.x * blockDim.x + threadIdx.x;
    int wv = gtid >> 6;
    if ((threadIdx.x & 63) == 0 && (wv << 6) < N) {
        *(unsigned long long*)(zrow_new + (wv << 1)) = m;
        if (m) atomicAdd(scnt_new, __popcll(m));
    }
}

// ---------------------------------------------------------------------------
// Launcher
// ---------------------------------------------------------------------------

extern "C" void kernel_launch(void* const* d_in, const int* in_sizes, int n_in,
                              void* d_out, int out_size, void* d_ws, size_t ws_size,
                              hipStream_t stream)
{
    const float* weights        = (const float*)d_in[0];
    const float* edge_basis     = (const float*)d_in[1];
    const float* ext_input      = (const float*)d_in[2];
    const float* decay          = (const float*)d_in[3];
    const float* current_factor = (const float*)d_in[4];
    const float* gathered_g     = (const float*)d_in[5];
    const float* v_th           = (const float*)d_in[6];
    const float* v_reset        = (const float*)d_in[7];
    const float* normalizer     = (const float*)d_in[8];
    const float* t_ref          = (const float*)d_in[9];
    const float* exp_dt_k       = (const float*)d_in[10];
    const float* asc_amps       = (const float*)d_in[11];
    const float* syn_decay      = (const float*)d_in[12];
    const float* psc_initial    = (const float*)d_in[13];
    const int*   pre_idx        = (const int*)d_in[14];
    const int*   post_idx       = (const int*)d_in[15];

    const int E  = in_sizes[0];
    const int N  = in_sizes[3];
    const int n5 = N * NB_;
    const int T  = in_sizes[2] / n5;            // B = 1

    const int words64   = (N + 63) / 64;        // 782
    const int words32   = words64 * 2;          // 1564
    const int bitstride = words32 * 32;         // 50048
    const int NC        = (N + CSL - 1) / CSL;  // 391

    float* out = (float*)d_out;

    // ---- workspace layout ---------------------------------------------------
    char* wsb = (char*)d_ws;
    size_t o = 0;
    // zero group (one small memset):
    int* chist = (int*)(wsb + o);  o += 512 * 4;
    int* scnt  = (int*)(wsb + o);  o += (size_t)(T + MD_) * 4;
    o = (o + 15) & ~(size_t)15;
    unsigned* zbits = (unsigned*)(wsb + o);
    size_t zero_bytes = o + (size_t)MD_ * words32 * 4;   // zbits head (rows 0..4)
    o += (size_t)(T + MD_) * words32 * 4;
    // non-zeroed:
    o = (o + 15) & ~(size_t)15;
    float*  psc         = (float*)(wsb + o);  o += (size_t)n5 * 4;
    float*  v           = (float*)(wsb + o);  o += (size_t)N * 4;
    float*  r           = (float*)(wsb + o);  o += (size_t)N * 4;
    float*  asc         = (float*)(wsb + o);  o += (size_t)2 * N * 4;
    float4* pk          = (float4*)(wsb + o); o += (size_t)N * 12 * 4;
    int*    row_ptr     = (int*)(wsb + o);    o += (size_t)N * 4;
    int*    coarse_base = (int*)(wsb + o);    o += 513 * 4;
    int*    coarse_ptr  = (int*)(wsb + o);    o += 512 * 4;
    o = (o + 15) & ~(size_t)15;
    uint2*    part      = (uint2*)(wsb + o);    o += (size_t)E * 8;
    unsigned* inSlot    = (unsigned*)(wsb + o); o += (size_t)E * 4;
    unsigned* inEid     = (unsigned*)(wsb + o); o += (size_t)E * 4;

    // ---- build (every launch; graph replays everything) --------------------
    hipMemsetAsync(d_ws, 0, zero_bytes, stream);   // ~34 KB

    init_kernel<<<(N + 255) / 256, 256, 0, stream>>>(
        decay, current_factor, gathered_g, v_th, v_reset, normalizer, t_ref,
        exp_dt_k, asc_amps, pk, v, r, asc, psc, N);

    const int nbe = (E + CH - 1) / CH;   // 489
    coarse_hist_kernel<<<nbe, 256, 0, stream>>>(post_idx, chist, E);
    scan_coarse_kernel<<<1, 256, 0, stream>>>(chist, coarse_base, coarse_ptr, NC);
    partition_kernel<<<nbe, 256, 0, stream>>>(
        pre_idx, post_idx, coarse_ptr, part, E, N, bitstride);
    bucket_sort_kernel<<<NC, 256, 0, stream>>>(
        coarse_base, part, inSlot, inEid, row_ptr, N);

    // ---- time loop: ONE lean kernel per step --------------------------------
    const int nblk = (N + 255) / 256;    // 196
    for (int t = 0; t < T; ++t) {
        step_kernel<<<nblk, 256, 0, stream>>>(
            ext_input + (size_t)t * n5,
            psc, syn_decay, psc_initial,
            pk, v, r, asc,
            scnt + t, scnt + t + MD_,
            zbits + (size_t)t * words32,
            zbits + (size_t)(t + MD_ - 1) * words32,
            zbits + (size_t)(t + MD_) * words32,
            row_ptr, inSlot, inEid, weights, edge_basis,
            out + (size_t)t * N,
            N);
    }
}